// Round 18
// baseline (88.278 us; speedup 1.0000x reference)
//
#include <hip/hip_runtime.h>
#include <hip/hip_bf16.h>

// MechanicsPINN: residual = EI*biharm(f) + GC*lap(f) + KC*f - P,
// f = MLP(x) 2->256->512->1024->65536, B=64, grid 256x256. All inputs fp32.
// Round 18: R17 + K-step 64 (half the barriers) + split-wait sub-phases.
//  - W tile 64x128 fp32, 2x32KB LDS double-buffer (2 blocks/CU kept).
//  - A via global->register prefetch (L2-hot, R9-proven); no A LDS tile.
//  - per step: issue [A(s+1) x8][W k0-31 x4][W k32-63 x4];
//    vmcnt(20) -> barrier -> compute k0-31 (second half W lands under it)
//    -> vmcnt(16) -> barrier -> compute k32-63 -> end barrier.
//  - 3 barriers per 64-k (was 4); counted waits never drain until the tail.

#define BATCH 64
#define NPIX 65536

typedef __attribute__((ext_vector_type(8))) short short8_t;  // bf16 x8 (4 VGPR)
typedef __attribute__((ext_vector_type(4))) float f32x4;

__device__ __forceinline__ short f2bf(float x) {  // fp32 -> bf16 RNE (native)
    __hip_bfloat16 h = __float2bfloat16(x);
    short s;
    __builtin_memcpy(&s, &h, 2);
    return s;
}

// -------- Fused layers 1+2: h2 = relu(relu(x@W1+b1) @ W2 + b2) --------
__global__ void k_layer12(const float* __restrict__ x, const float* __restrict__ W1,
                          const float* __restrict__ b1, const float* __restrict__ W2,
                          const float* __restrict__ b2, float* __restrict__ h2) {
    __shared__ float As[16][64];
    __shared__ float Ws[64][16];
    int tid = threadIdx.x;
    int tn = tid & 15, tm = tid >> 4;
    int n0 = blockIdx.x * 16, m0 = blockIdx.y * 16;
    float acc = 0.f;
    for (int k0 = 0; k0 < 256; k0 += 64) {
#pragma unroll
        for (int j = 0; j < 4; ++j) {          // build h1 16x64 tile on the fly
            int e = j * 256 + tid;
            int m = m0 + (e >> 6), kk = k0 + (e & 63);
            float v = x[m * 2 + 0] * W1[kk] + x[m * 2 + 1] * W1[256 + kk] + b1[kk];
            As[e >> 6][e & 63] = v > 0.f ? v : 0.f;
        }
#pragma unroll
        for (int j = 0; j < 4; ++j) {          // stage W2 64x16
            int e = j * 256 + tid;
            Ws[e >> 4][e & 15] = W2[(k0 + (e >> 4)) * 512 + n0 + (e & 15)];
        }
        __syncthreads();
#pragma unroll
        for (int k = 0; k < 64; ++k)
            acc += As[tm][k] * Ws[k][tn];
        __syncthreads();
    }
    acc += b2[n0 + tn];
    acc = acc > 0.f ? acc : 0.f;
    h2[(m0 + tm) * 512 + n0 + tn] = acc;
}

// -------- Layer 3: h3b(bf16) = relu(h2 @ W3 + b3), K=512, N=1024 --------
__global__ void k_layer3(const float* __restrict__ A, const float* __restrict__ Wt,
                         const float* __restrict__ bias, short* __restrict__ out_bf) {
    __shared__ float As[16][64];
    __shared__ float Ws[64][16];
    int tid = threadIdx.x;
    int tn = tid & 15, tm = tid >> 4;
    int n0 = blockIdx.x * 16, m0 = blockIdx.y * 16;
    float acc = 0.f;
    for (int k0 = 0; k0 < 512; k0 += 64) {
#pragma unroll
        for (int j = 0; j < 4; ++j) {
            int e = j * 256 + tid;
            As[e >> 6][e & 63] = A[(m0 + (e >> 6)) * 512 + k0 + (e & 63)];
        }
#pragma unroll
        for (int j = 0; j < 4; ++j) {
            int e = j * 256 + tid;
            Ws[e >> 4][e & 15] = Wt[(k0 + (e >> 4)) * 1024 + n0 + (e & 15)];
        }
        __syncthreads();
#pragma unroll
        for (int k = 0; k < 64; ++k)
            acc += As[tm][k] * Ws[k][tn];
        __syncthreads();
    }
    acc += bias[n0 + tn];
    acc = acc > 0.f ? acc : 0.f;
    out_bf[(m0 + tm) * 1024 + n0 + tn] = f2bf(acc);
}

// ---------- Main GEMM: f = h3b @ W4 + b4 (bf16 MFMA, M=64,N=65536,K=1024) ----
// 256 thr / 4 waves; block tile = 128 cols x 64 m; K-step 64 (16 steps).
// Wave w owns cols w*32..+31: per step 2 col-tiles x 4 m-tiles x 2 ksub
// = 16 MFMA. A-frags global->reg, W via global_load_lds (512B segments).
__global__ __launch_bounds__(256) void k_gemm_mfma(
        const short* __restrict__ A,     // h3 bf16 [64][1024]
        const float* __restrict__ W,     // W4 fp32 [1024][65536]
        const float* __restrict__ bias,  // [65536]
        float* __restrict__ f) {         // [64][65536]
    __shared__ float Wt[2][64 * 128];    // 32 KB per buffer, [k][col^swz]
    const int tid = threadIdx.x;
    const int w = tid >> 6;
    const int lane = tid & 63;
    const int lr = lane & 15;
    const int g = lane >> 4;             // k-group 0..3
    const int n0 = blockIdx.x * 128;

    f32x4 acc[4][2];                     // [m-tile][col-tile]
#pragma unroll
    for (int a = 0; a < 4; ++a)
#pragma unroll
        for (int b = 0; b < 2; ++b)
            acc[a][b] = {0.f, 0.f, 0.f, 0.f};

    // A-frag (mt,ksub) at step s: A[(mt*16+lr)*1024 + s*64 + ksub*32 + g*8 ..+7]
    const short* ap = A + lr * 1024 + g * 8;
    short8_t aC[4][2], aN[4][2];

    auto loadA = [&](short8_t (&dst)[4][2], int s) {
#pragma unroll
        for (int mt = 0; mt < 4; ++mt)
#pragma unroll
            for (int ks = 0; ks < 2; ++ks)
                dst[mt][ks] = *(const short8_t*)(ap + mt * 16384 + s * 64 + ks * 32);
    };

    // stage W step s into buffer b: 8 chunks/thread; i 0..3 = k 0..31 (first
    // half), i 4..7 = k 32..63. Source pre-swizzled (col bit4 ^= k bit3).
    auto stageW = [&](int b, int s, int ilo, int ihi) {
#pragma unroll
        for (int i = 0; i < 8; ++i) {
            if (i < ilo || i >= ihi) continue;
            int c = i * 256 + tid;                 // 0..2047
            int k = c >> 5;                        // 0..63
            int q4 = (c & 31) * 4;
            int csw = q4 ^ (((k >> 3) & 1) << 4);
            const float* src = W + (size_t)(s * 64 + k) * NPIX + n0 + csw;
            __builtin_amdgcn_global_load_lds(
                (const __attribute__((address_space(1))) void*)src,
                (__attribute__((address_space(3))) void*)((char*)&Wt[b][0] + c * 16),
                16, 0, 0);
        }
    };

    auto computeHalf = [&](int cur, int ks, short8_t (&aa)[4][2]) {
#pragma unroll
        for (int t = 0; t < 2; ++t) {
            const int csw = (w * 32 + t * 16 + lr) ^ ((g & 1) << 4);
            short8_t bfr;
#pragma unroll
            for (int j = 0; j < 8; ++j)
                bfr[j] = f2bf(Wt[cur][(ks * 32 + g * 8 + j) * 128 + csw]);
#pragma unroll
            for (int mt = 0; mt < 4; ++mt)
                acc[mt][t] = __builtin_amdgcn_mfma_f32_16x16x32_bf16(aa[mt][ks], bfr, acc[mt][t], 0, 0, 0);
        }
    };

    // prologue: A(0) regs, W(0) staged
    loadA(aC, 0);
    __builtin_amdgcn_sched_barrier(0);
    stageW(0, 0, 0, 8);
    __builtin_amdgcn_sched_barrier(0);

    for (int s = 0; s < 16; ++s) {
        const int cur = s & 1;
        if (s < 15) {
            loadA(aN, s + 1);                      // 8 reg loads (oldest of new)
            __builtin_amdgcn_sched_barrier(0);
            stageW(cur ^ 1, s + 1, 0, 4);          // W first half
            __builtin_amdgcn_sched_barrier(0);
            stageW(cur ^ 1, s + 1, 4, 8);          // W second half
            __builtin_amdgcn_sched_barrier(0);
            // in flight <= A(s)8+W(s)8 + new 16; A(s)+Wfirst(s) done at 20
            asm volatile("s_waitcnt vmcnt(20)" ::: "memory");
        } else {
            asm volatile("s_waitcnt vmcnt(4)" ::: "memory");
        }
        __builtin_amdgcn_sched_barrier(0);
        __builtin_amdgcn_s_barrier();              // first half of cur ready
        __builtin_amdgcn_sched_barrier(0);
        computeHalf(cur, 0, aC);
        if (s < 15)
            asm volatile("s_waitcnt vmcnt(16)" ::: "memory");  // second half landed
        else
            asm volatile("s_waitcnt vmcnt(0)" ::: "memory");
        __builtin_amdgcn_sched_barrier(0);
        __builtin_amdgcn_s_barrier();              // second half of cur ready
        __builtin_amdgcn_sched_barrier(0);
        computeHalf(cur, 1, aC);
        if (s < 15) {
#pragma unroll
            for (int mt = 0; mt < 4; ++mt)
#pragma unroll
                for (int ks = 0; ks < 2; ++ks)
                    aC[mt][ks] = aN[mt][ks];       // auto-wait vmcnt(8): A(s+1)
        }
        __builtin_amdgcn_sched_barrier(0);
        __builtin_amdgcn_s_barrier();              // all reads of cur done
        __builtin_amdgcn_sched_barrier(0);
    }

    // ---- coalesced epilogue: dump C (+bias) to 32KB LDS, store 512B rows ----
    float* Cl = (float*)&Wt[0][0];       // 64 rows x 128 cols = 32 KB
#pragma unroll
    for (int t = 0; t < 2; ++t) {
        const int colb = w * 32 + t * 16 + lr;
        float bb = bias[n0 + colb];
#pragma unroll
        for (int mt = 0; mt < 4; ++mt)
#pragma unroll
            for (int r = 0; r < 4; ++r)
                Cl[(mt * 16 + g * 4 + r) * 128 + colb] = acc[mt][t][r] + bb;
    }
    __syncthreads();
#pragma unroll
    for (int it = 0; it < 8; ++it) {     // 256 thr: 32-lane group per row
        int row = (tid >> 5) + it * 8;   // 0..63
        int cc = (tid & 31) * 4;         // float offset 0..124
        f32x4 v = *(const f32x4*)&Cl[row * 128 + cc];
        *(f32x4*)(f + (size_t)row * NPIX + n0 + cc) = v;
    }
}

// --------------------------- Stencil (two-phase) ---------------------------
#define ROWS 16
__device__ __forceinline__ int rfl(int i) {
    return i < 0 ? -i : (i > 255 ? 510 - i : i);
}
__global__ void k_stencil(const float* __restrict__ f, const float* __restrict__ P,
                          float* __restrict__ out) {
    __shared__ float fs[ROWS + 4][256];
    __shared__ float ls[ROWS + 2][256];
    int x = threadIdx.x;
    int y0 = blockIdx.x * ROWS;
    int b = blockIdx.y;
    const float* fb = f + (size_t)b * NPIX;
#pragma unroll
    for (int t = 0; t < ROWS + 4; ++t) {
        int gy = rfl(y0 - 2 + t);
        fs[t][x] = fb[gy * 256 + x];
    }
    __syncthreads();

    int xm = x == 0 ? 1 : x - 1;
    int xp = x == 255 ? 254 : x + 1;

#pragma unroll
    for (int t = 0; t < ROWS + 2; ++t) {
        int jj = rfl(y0 - 1 + t);
        int s  = jj - y0 + 2;
        int sm = rfl(jj - 1) - y0 + 2;
        int sp = rfl(jj + 1) - y0 + 2;
        float c = fs[s][x];
        ls[t][x] = (fs[sm][x] - 2.f * c + fs[sp][x]) +
                   (fs[s][xm] - 2.f * c + fs[s][xp]);
    }
    __syncthreads();

#pragma unroll
    for (int r = 0; r < ROWS; ++r) {
        int y = y0 + r;
        float lc = ls[r + 1][x];
        float bih = (ls[r][x] - 2.f * lc + ls[r + 2][x]) +
                    (ls[r + 1][xm] - 2.f * lc + ls[r + 1][xp]);
        float fc = fs[r + 2][x];
        size_t idx = (size_t)b * NPIX + y * 256 + x;
        out[idx] = bih + lc + fc - P[idx];
    }
}

extern "C" void kernel_launch(void* const* d_in, const int* in_sizes, int n_in,
                              void* d_out, int out_size, void* d_ws, size_t ws_size,
                              hipStream_t stream) {
    const float* x  = (const float*)d_in[0];
    const float* P  = (const float*)d_in[1];
    const float* W1 = (const float*)d_in[2];
    const float* b1 = (const float*)d_in[3];
    const float* W2 = (const float*)d_in[4];
    const float* b2 = (const float*)d_in[5];
    const float* W3 = (const float*)d_in[6];
    const float* b3 = (const float*)d_in[7];
    const float* W4 = (const float*)d_in[8];
    const float* b4 = (const float*)d_in[9];
    float* out = (float*)d_out;

    char* ws = (char*)d_ws;
    float* h2  = (float*)(ws);                      // 64*512*4  = 128 KB
    short* h3b = (short*)(ws + (128 << 10));        // 64*1024*2 = 128 KB (bf16)
    float* f   = (float*)(ws + (256 << 10));        // 64*65536*4 = 16 MB

    k_layer12<<<dim3(512 / 16, 4), 256, 0, stream>>>(x, W1, b1, W2, b2, h2);
    k_layer3<<<dim3(1024 / 16, 4), 256, 0, stream>>>(h2, W3, b3, h3b);
    k_gemm_mfma<<<NPIX / 128, 256, 0, stream>>>(h3b, W4, b4, f);
    k_stencil<<<dim3(256 / ROWS, BATCH), 256, 0, stream>>>(f, P, out);
}

// Round 19
// 77.945 us; speedup vs baseline: 1.1326x; 1.1326x over previous
//
#include <hip/hip_runtime.h>
#include <hip/hip_bf16.h>

// MechanicsPINN: residual = EI*biharm(f) + GC*lap(f) + KC*f - P,
// f = MLP(x) 2->256->512->1024->65536, B=64, grid 256x256. All inputs fp32.
// Round 19: gemm + stencil = R17 EXACT (82.0 us best; gemm at its
// 512B-panel memory wall, proven across 4 sync structures).
// New: k_layer3 as single-wave MFMA (grid 64 x 64thr, zero barriers,
// counted vmcnt(6) double-buffer); layer12 emits h2 in bf16 for it.

#define BATCH 64
#define NPIX 65536

typedef __attribute__((ext_vector_type(8))) short short8_t;  // bf16 x8 (4 VGPR)
typedef __attribute__((ext_vector_type(4))) float f32x4;

__device__ __forceinline__ short f2bf(float x) {  // fp32 -> bf16 RNE (native)
    __hip_bfloat16 h = __float2bfloat16(x);
    short s;
    __builtin_memcpy(&s, &h, 2);
    return s;
}

// -------- Fused layers 1+2: h2b = bf16(relu(relu(x@W1+b1) @ W2 + b2)) --------
__global__ void k_layer12(const float* __restrict__ x, const float* __restrict__ W1,
                          const float* __restrict__ b1, const float* __restrict__ W2,
                          const float* __restrict__ b2, short* __restrict__ h2b) {
    __shared__ float As[16][64];
    __shared__ float Ws[64][16];
    int tid = threadIdx.x;
    int tn = tid & 15, tm = tid >> 4;
    int n0 = blockIdx.x * 16, m0 = blockIdx.y * 16;
    float acc = 0.f;
    for (int k0 = 0; k0 < 256; k0 += 64) {
#pragma unroll
        for (int j = 0; j < 4; ++j) {          // build h1 16x64 tile on the fly
            int e = j * 256 + tid;
            int m = m0 + (e >> 6), kk = k0 + (e & 63);
            float v = x[m * 2 + 0] * W1[kk] + x[m * 2 + 1] * W1[256 + kk] + b1[kk];
            As[e >> 6][e & 63] = v > 0.f ? v : 0.f;
        }
#pragma unroll
        for (int j = 0; j < 4; ++j) {          // stage W2 64x16
            int e = j * 256 + tid;
            Ws[e >> 4][e & 15] = W2[(k0 + (e >> 4)) * 512 + n0 + (e & 15)];
        }
        __syncthreads();
#pragma unroll
        for (int k = 0; k < 64; ++k)
            acc += As[tm][k] * Ws[k][tn];
        __syncthreads();
    }
    acc += b2[n0 + tn];
    acc = acc > 0.f ? acc : 0.f;
    h2b[(m0 + tm) * 512 + n0 + tn] = f2bf(acc);
}

// -------- Layer 3 (MFMA): h3b = bf16(relu(h2b @ W3 + b3)), M=64,K=512,N=1024 --
// Grid 64 x 64 thr (1 wave). Wave owns 16 cols x all 64 m (4 MFMA/step),
// 16 K-steps of 32. W3 staged 32x16 fp32 (2KB) double-buffered via
// global_load_lds; A-frags straight from global (L2-hot). ZERO barriers:
// single wave -> counted vmcnt is the only sync needed.
__global__ __launch_bounds__(64) void k_layer3(
        const short* __restrict__ A,     // h2b bf16 [64][512]
        const float* __restrict__ W3,    // [512][1024]
        const float* __restrict__ b3,    // [1024]
        short* __restrict__ h3b) {       // [64][1024] bf16
    __shared__ float Wt[2][32 * 16];     // 2KB per buffer, [k][col]
    const int lane = threadIdx.x;
    const int lr = lane & 15;
    const int g = lane >> 4;             // k-group 0..3
    const int n0 = blockIdx.x * 16;

    f32x4 acc[4];
#pragma unroll
    for (int a = 0; a < 4; ++a) acc[a] = {0.f, 0.f, 0.f, 0.f};

    const short* ap = A + lr * 512 + g * 8;   // frag(mt,s): + mt*8192 + s*32

    auto stage = [&](int b, int s) {
#pragma unroll
        for (int i = 0; i < 2; ++i) {
            int c = i * 64 + lane;             // 0..127
            int k = c >> 2, q = c & 3;         // 4 chunks (64B) per k-row
            const float* src = W3 + (size_t)(s * 32 + k) * 1024 + n0 + q * 4;
            __builtin_amdgcn_global_load_lds(
                (const __attribute__((address_space(1))) void*)src,
                (__attribute__((address_space(3))) void*)((char*)&Wt[b][0] + c * 16),
                16, 0, 0);
        }
    };

    short8_t aC[4], aN[4];
    stage(0, 0);
#pragma unroll
    for (int mt = 0; mt < 4; ++mt)
        aC[mt] = *(const short8_t*)(ap + mt * 8192);

    for (int s = 0; s < 16; ++s) {
        const int cur = s & 1;
        if (s < 15) {
            stage(cur ^ 1, s + 1);             // 2 instrs
#pragma unroll
            for (int mt = 0; mt < 4; ++mt)     // 4 instrs (A(s+1))
                aN[mt] = *(const short8_t*)(ap + mt * 8192 + (s + 1) * 32);
            // queue: [W(s)2, A(s)4(retired via aC), W(s+1)2, A(s+1)4]
            asm volatile("s_waitcnt vmcnt(6)" ::: "memory");  // W(s)+A(s) landed
        } else {
            asm volatile("s_waitcnt vmcnt(0)" ::: "memory");
        }
        __builtin_amdgcn_sched_barrier(0);

        short8_t bfr;
#pragma unroll
        for (int j = 0; j < 8; ++j)            // col=lr, k=g*8+j
            bfr[j] = f2bf(Wt[cur][(g * 8 + j) * 16 + lr]);
#pragma unroll
        for (int mt = 0; mt < 4; ++mt)
            acc[mt] = __builtin_amdgcn_mfma_f32_16x16x32_bf16(aC[mt], bfr, acc[mt], 0, 0, 0);

        if (s < 15) {
#pragma unroll
            for (int mt = 0; mt < 4; ++mt) aC[mt] = aN[mt];
        }
    }

    // C/D: col = lane&15, row = g*4 + r per m-tile
    float bb = b3[n0 + lr];
#pragma unroll
    for (int mt = 0; mt < 4; ++mt) {
        int rowb = mt * 16 + g * 4;
#pragma unroll
        for (int r = 0; r < 4; ++r) {
            float v = acc[mt][r] + bb;
            v = v > 0.f ? v : 0.f;             // relu
            h3b[(rowb + r) * 1024 + n0 + lr] = f2bf(v);
        }
    }
}

// ---------- Main GEMM: f = h3b @ W4 + b4 (bf16 MFMA, M=64,N=65536,K=1024) ----
// R17 EXACT. 256 thr / 4 waves; block tile = 128 cols x 64 m.
__global__ __launch_bounds__(256) void k_gemm_mfma(
        const short* __restrict__ A,     // h3 bf16 [64][1024]
        const float* __restrict__ W,     // W4 fp32 [1024][65536]
        const float* __restrict__ bias,  // [65536]
        float* __restrict__ f) {         // [64][65536]
    __shared__ float Wt[2][32 * 128];    // 16 KB per buffer, [k][col^swz]
    __shared__ short At[2][4 * 64 * 8];  // 4 KB per buffer, [kq][m^swz][8]
    const int tid = threadIdx.x;
    const int w = tid >> 6;
    const int lane = tid & 63;
    const int lr = lane & 15;
    const int g = lane >> 4;             // k-group 0..3
    const int n0 = blockIdx.x * 128;

    f32x4 acc[4][2];                     // [m-tile][col-tile]
#pragma unroll
    for (int a = 0; a < 4; ++a)
#pragma unroll
        for (int b = 0; b < 2; ++b)
            acc[a][b] = {0.f, 0.f, 0.f, 0.f};

    // stage step s into buffer b: 4 W-chunks + 1 A-chunk per thread (16B each)
    auto stage = [&](int b, int s) {
#pragma unroll
        for (int i = 0; i < 4; ++i) {
            int c = i * 256 + tid;                 // 0..1023
            int k = c >> 5;                        // 0..31
            int q4 = (c & 31) * 4;                 // float col-group
            int csw = q4 ^ (((k >> 3) & 1) << 4);  // source pre-swizzle (bit4)
            const float* src = W + (size_t)(s * 32 + k) * NPIX + n0 + csw;
            __builtin_amdgcn_global_load_lds(
                (const __attribute__((address_space(1))) void*)src,
                (__attribute__((address_space(3))) void*)((char*)&Wt[b][0] + c * 16),
                16, 0, 0);
        }
        {
            int kq = tid >> 6;                     // 0..3
            int ms = tid & 63;
            int md = ms ^ (kq << 2);               // source m pre-swizzle
            const short* asrc = A + md * 1024 + s * 32 + kq * 8;
            __builtin_amdgcn_global_load_lds(
                (const __attribute__((address_space(1))) void*)asrc,
                (__attribute__((address_space(3))) void*)((char*)&At[b][0] + tid * 16),
                16, 0, 0);
        }
    };

    stage(0, 0);

    for (int s = 0; s < 32; ++s) {
        const int cur = s & 1;
        if (s < 31) {
            stage(cur ^ 1, s + 1);
            asm volatile("s_waitcnt vmcnt(5)" ::: "memory");  // stage(s) landed
        } else {
            asm volatile("s_waitcnt vmcnt(0)" ::: "memory");
        }
        __builtin_amdgcn_sched_barrier(0);
        __builtin_amdgcn_s_barrier();    // everyone's stage(s) landed
        __builtin_amdgcn_sched_barrier(0);

        // A-frags: [kq=g][(mrow^(g<<2))]
        short8_t afr[4];
#pragma unroll
        for (int mt = 0; mt < 4; ++mt) {
            int mrow = mt * 16 + lr;
            afr[mt] = *(const short8_t*)((const short*)&At[cur][0] +
                                         g * 512 + (mrow ^ (g << 2)) * 8);
        }
#pragma unroll
        for (int t = 0; t < 2; ++t) {
            const int col = w * 32 + t * 16 + lr;
            const int csw = col ^ ((g & 1) << 4);  // undo bit-4 swizzle
            short8_t bfr;
#pragma unroll
            for (int j = 0; j < 8; ++j)
                bfr[j] = f2bf(Wt[cur][(g * 8 + j) * 128 + csw]);
#pragma unroll
            for (int mt = 0; mt < 4; ++mt)
                acc[mt][t] = __builtin_amdgcn_mfma_f32_16x16x32_bf16(afr[mt], bfr, acc[mt][t], 0, 0, 0);
        }
        __builtin_amdgcn_s_barrier();    // reads of cur done before overwrite
    }

    // ---- coalesced epilogue: dump C (+bias) to 32KB LDS, store 512B rows ----
    __syncthreads();
    float* Cl = (float*)&Wt[0][0];       // 64 rows x 128 cols = 32 KB
#pragma unroll
    for (int t = 0; t < 2; ++t) {
        const int colb = w * 32 + t * 16 + lr;
        float bb = bias[n0 + colb];
#pragma unroll
        for (int mt = 0; mt < 4; ++mt)
#pragma unroll
            for (int r = 0; r < 4; ++r)
                Cl[(mt * 16 + g * 4 + r) * 128 + colb] = acc[mt][t][r] + bb;
    }
    __syncthreads();
#pragma unroll
    for (int it = 0; it < 8; ++it) {     // 256 thr: 32-lane group per row
        int row = (tid >> 5) + it * 8;   // 0..63
        int cc = (tid & 31) * 4;         // float offset 0..124
        f32x4 v = *(const f32x4*)&Cl[row * 128 + cc];
        *(f32x4*)(f + (size_t)row * NPIX + n0 + cc) = v;
    }
}

// --------------------------- Stencil (two-phase, R17 exact) ------------------
#define ROWS 16
__device__ __forceinline__ int rfl(int i) {
    return i < 0 ? -i : (i > 255 ? 510 - i : i);
}
__global__ void k_stencil(const float* __restrict__ f, const float* __restrict__ P,
                          float* __restrict__ out) {
    __shared__ float fs[ROWS + 4][256];
    __shared__ float ls[ROWS + 2][256];
    int x = threadIdx.x;
    int y0 = blockIdx.x * ROWS;
    int b = blockIdx.y;
    const float* fb = f + (size_t)b * NPIX;
#pragma unroll
    for (int t = 0; t < ROWS + 4; ++t) {
        int gy = rfl(y0 - 2 + t);
        fs[t][x] = fb[gy * 256 + x];
    }
    __syncthreads();

    int xm = x == 0 ? 1 : x - 1;
    int xp = x == 255 ? 254 : x + 1;

#pragma unroll
    for (int t = 0; t < ROWS + 2; ++t) {
        int jj = rfl(y0 - 1 + t);
        int s  = jj - y0 + 2;
        int sm = rfl(jj - 1) - y0 + 2;
        int sp = rfl(jj + 1) - y0 + 2;
        float c = fs[s][x];
        ls[t][x] = (fs[sm][x] - 2.f * c + fs[sp][x]) +
                   (fs[s][xm] - 2.f * c + fs[s][xp]);
    }
    __syncthreads();

#pragma unroll
    for (int r = 0; r < ROWS; ++r) {
        int y = y0 + r;
        float lc = ls[r + 1][x];
        float bih = (ls[r][x] - 2.f * lc + ls[r + 2][x]) +
                    (ls[r + 1][xm] - 2.f * lc + ls[r + 1][xp]);
        float fc = fs[r + 2][x];
        size_t idx = (size_t)b * NPIX + y * 256 + x;
        out[idx] = bih + lc + fc - P[idx];
    }
}

extern "C" void kernel_launch(void* const* d_in, const int* in_sizes, int n_in,
                              void* d_out, int out_size, void* d_ws, size_t ws_size,
                              hipStream_t stream) {
    const float* x  = (const float*)d_in[0];
    const float* P  = (const float*)d_in[1];
    const float* W1 = (const float*)d_in[2];
    const float* b1 = (const float*)d_in[3];
    const float* W2 = (const float*)d_in[4];
    const float* b2 = (const float*)d_in[5];
    const float* W3 = (const float*)d_in[6];
    const float* b3 = (const float*)d_in[7];
    const float* W4 = (const float*)d_in[8];
    const float* b4 = (const float*)d_in[9];
    float* out = (float*)d_out;

    char* ws = (char*)d_ws;
    short* h2b = (short*)(ws);                      // 64*512*2  = 64 KB
    short* h3b = (short*)(ws + (128 << 10));        // 64*1024*2 = 128 KB (bf16)
    float* f   = (float*)(ws + (256 << 10));        // 64*65536*4 = 16 MB

    k_layer12<<<dim3(512 / 16, 4), 256, 0, stream>>>(x, W1, b1, W2, b2, h2b);
    k_layer3<<<64, 64, 0, stream>>>(h2b, W3, b3, h3b);
    k_gemm_mfma<<<NPIX / 128, 256, 0, stream>>>(h3b, W4, b4, f);
    k_stencil<<<dim3(256 / ROWS, BATCH), 256, 0, stream>>>(f, P, out);
}